// Round 12
// baseline (4028.509 us; speedup 1.0000x reference)
//
#include <hip/hip_runtime.h>
#include <hip/hip_bf16.h>

#define Hn   89
#define Tn   120
#define BM   128
#define LDP  104   // bf16 pitch: 208B rows, 16B-aligned
#define NTHR 768   // 12 waves = 3 jt-pairs x 4 row-quarters; grid=256 -> 1 block/CU

using bf16   = __bf16;
using bf16x4 = __attribute__((ext_vector_type(4))) __bf16;
using bf16x8 = __attribute__((ext_vector_type(8))) __bf16;
typedef __attribute__((ext_vector_type(4))) float f32x4;

#define SRZ (-1.44269504f)   // r/z pre-scale: sig(x) = rcp(1+exp2(-log2e*x))
#define SNN ( 2.88539008f)   // n pre-scale: tanh(x) = 1-2*rcp(1+exp2(2log2e*x))

__device__ __forceinline__ f32x4 ld4(const float* p) {   // 4B-aligned 16B load
  f32x4 v; __builtin_memcpy(&v, p, 16); return v;
}
__device__ __forceinline__ bf16x8 pack8(f32x4 a, f32x4 b) {
  bf16x8 r;
  r[0]=(bf16)a[0]; r[1]=(bf16)a[1]; r[2]=(bf16)a[2]; r[3]=(bf16)a[3];
  r[4]=(bf16)b[0]; r[5]=(bf16)b[1]; r[6]=(bf16)b[2]; r[7]=(bf16)b[3];
  return r;
}
__device__ __forceinline__ float frcp(float x) { return __builtin_amdgcn_rcpf(x); }
__device__ __forceinline__ float fex2(float x) { return __builtin_amdgcn_exp2f(x); }
__device__ __forceinline__ float fsig(float x) { return frcp(1.f + fex2(-1.44269504f * x)); }

// r8 structure + 2jt x 2mt wave tiling. 12 waves = 3 jt-pair groups (p) x 4
// row-quarters (rq). Each wave: rows [32rq,32rq+32) (2 mt), j cols
// [32p,32p+32) (2 jt). One set of xf/hf frag reads per mt feeds BOTH jt's
// MFMAs -> LDS reads halve vs r8 (12 b128/wave/step). Weights: 36 frags =
// 144 VGPR/wave. Swapped-operand MFMA (A=weights): lane owns 4 consecutive
// j for one batch row -> h-write = 1 aligned ds_write_b64 per (mt,jt).
// 2-deep X staging: { BAR; commit X(t+1) (regs from t-1); issue X(t+2);
// compute }. Biases via X col89==1.0 (kt=2, ih side); b_hn as register fma.
__global__ __launch_bounds__(NTHR, 3)
void gru_fused(const float* __restrict__ X,    // [B][T][89]
               const float* __restrict__ Wih,  // [267][89]
               const float* __restrict__ Whh,  // [267][89]
               const float* __restrict__ bih,  // [267]
               const float* __restrict__ bhh,  // [267]
               const float* __restrict__ Wm,   // [32][89]
               const float* __restrict__ bm,   // [32]
               const float* __restrict__ Wo,   // [32]
               const float* __restrict__ bo,   // [1]
               float* __restrict__ Y,          // [B] mscore | [B][32] mmetric
               int Bt)
{
  __shared__ __align__(16) bf16 Xl[2][BM][LDP];
  __shared__ __align__(16) bf16 Hl[2][BM][LDP];
  __shared__ float Ml[BM][32];

  const int tid  = threadIdx.x;
  const int lane = tid & 63;
  const int wv   = tid >> 6;       // 0..11
  const int p    = wv >> 2;        // jt-pair group 0..2 (j cols 32p..32p+31)
  const int rq   = wv & 3;         // row quarter (rows 32rq..32rq+31)
  const int l15  = lane & 15;
  const int kg   = lane >> 4;      // 0..3
  const size_t brow0 = (size_t)blockIdx.x * BM;

  // ---- weights -> persistent A-frags; ih k==89 carries biases; pre-scaled ----
  bf16x8 Bf[2][3][2][3];  // [jtl][gate r/z/n][ih/hh][k-tile]
#pragma unroll
  for (int jtl = 0; jtl < 2; ++jtl) {
    const int jA = p * 32 + jtl * 16 + l15;
    const bool jAok = (jA < Hn);
#pragma unroll
    for (int g = 0; g < 3; ++g)
#pragma unroll
      for (int s = 0; s < 2; ++s) {
        const float* W = s ? Whh : Wih;
        const float sc = (g < 2) ? SRZ : SNN;
#pragma unroll
        for (int kt = 0; kt < 3; ++kt) {
          bf16x8 f;
          const int k0 = kt * 32 + kg * 8;
#pragma unroll
          for (int e = 0; e < 8; ++e) {
            const int k = k0 + e;
            float v = 0.f;
            if (jAok) {
              if (k < Hn) v = sc * W[(size_t)(g * Hn + jA) * Hn + k];
              else if (k == Hn && s == 0)   // pairs with X col89 == 1.0
                v = (g < 2) ? sc * (bih[g * Hn + jA] + bhh[g * Hn + jA])
                            : SNN * bih[2 * Hn + jA];
            }
            f[e] = (bf16)v;
          }
          Bf[jtl][g][s][kt] = f;
        }
      }
  }

  float bhnq[2][4];
#pragma unroll
  for (int jtl = 0; jtl < 2; ++jtl)
#pragma unroll
    for (int q = 0; q < 4; ++q) {
      const int j = p * 32 + jtl * 16 + kg * 4 + q;
      bhnq[jtl][q] = (j < Hn) ? SNN * bhh[2 * Hn + j] : 0.f;
    }

  // ---- X staging: 128 rows x 12 chunks of 8 f32; exactly 2 chunks/thread ----
  int soff0, soff1, loff0, loff1;
  bool lst0, lst1;
  {
    const int p0 = tid, p1 = tid + NTHR;
    const int r0 = p0 / 12, s0 = p0 - r0 * 12;
    const int r1 = p1 / 12, s1 = p1 - r1 * 12;
    lst0 = (s0 == 11); lst1 = (s1 == 11);
    soff0 = r0 * (Tn * Hn) + s0 * 8;  loff0 = r0 * LDP + s0 * 8;
    soff1 = r1 * (Tn * Hn) + s1 * 8;  loff1 = r1 * LDP + s1 * 8;
  }
  const float* Xb2 = X + brow0 * (size_t)(Tn * Hn);
  f32x4 A0, B0, A1, B1;

  auto issue = [&](int toff) {
    const float* p0 = Xb2 + soff0 + toff;
    const float* p1 = Xb2 + soff1 + toff;
    if (lst0) { f32x4 a = {p0[0], 1.0f, 0.f, 0.f}; A0 = a; B0 = (f32x4){0.f,0.f,0.f,0.f}; }
    else      { A0 = ld4(p0); B0 = ld4(p0 + 4); }
    if (lst1) { f32x4 a = {p1[0], 1.0f, 0.f, 0.f}; A1 = a; B1 = (f32x4){0.f,0.f,0.f,0.f}; }
    else      { A1 = ld4(p1); B1 = ld4(p1 + 4); }
  };
  auto commit = [&](int plane) {
    *(bf16x8*)(&Xl[plane][0][0] + loff0) = pack8(A0, B0);
    *(bf16x8*)(&Xl[plane][0][0] + loff1) = pack8(A1, B1);
  };

  float hold[2][2][4];   // [mtl][jtl][q], fp32 carry
#pragma unroll
  for (int mtl = 0; mtl < 2; ++mtl)
#pragma unroll
    for (int jtl = 0; jtl < 2; ++jtl)
#pragma unroll
      for (int q = 0; q < 4; ++q) hold[mtl][jtl][q] = 0.f;

  // lane-constant LDS bases
  bf16*       hwb = &Hl[0][0][0] + (rq * 32 + l15) * LDP + p * 32 + kg * 4;
  const bf16* xrb = &Xl[0][0][0] + (rq * 32 + l15) * LDP + kg * 8;
  const bf16* hrb = &Hl[0][0][0] + (rq * 32 + l15) * LDP + kg * 8;
  const int bufo = BM * LDP;

  // ---- prologue: X(0)->plane0; h(0)=0 -> plane0; X(1) in regs ----
  issue(0);
  commit(0);
  {
    const bf16x4 z4 = {(bf16)0.f, (bf16)0.f, (bf16)0.f, (bf16)0.f};
#pragma unroll
    for (int mtl = 0; mtl < 2; ++mtl)
#pragma unroll
      for (int jtl = 0; jtl < 2; ++jtl)
        *(bf16x4*)(hwb + mtl * 16 * LDP + jtl * 16) = z4;
  }
  issue(Hn);

  int toff = 2 * Hn;
  for (int t = 0; t < Tn; ++t) {
    const int b = t & 1;
    __syncthreads();                      // plane b holds X(t), h(t)
    if (t + 1 < Tn) commit(b ^ 1);        // X(t+1) -> plane b^1 (regs from t-1)
    if (t + 2 < Tn) { issue(toff); toff += Hn; }   // X(t+2): full step of slack

    __builtin_amdgcn_s_setprio(1);
    const bf16* xr = xrb + b * bufo;
    const bf16* hr = hrb + b * bufo;
    bf16*       hw = hwb + (b ^ 1) * bufo;
#pragma unroll
    for (int mtl = 0; mtl < 2; ++mtl) {
      // one frag-read set per row-tile, reused by BOTH jt's
      bf16x8 xf[3], hf[3];
#pragma unroll
      for (int kt = 0; kt < 3; ++kt) {
        xf[kt] = *(const bf16x8*)(xr + mtl * 16 * LDP + kt * 32);
        hf[kt] = *(const bf16x8*)(hr + mtl * 16 * LDP + kt * 32);
      }
#pragma unroll
      for (int jtl = 0; jtl < 2; ++jtl) {
        f32x4 ar = {0,0,0,0}, az = {0,0,0,0}, ain = {0,0,0,0}, ahn = {0,0,0,0};
#pragma unroll
        for (int kt = 0; kt < 3; ++kt) {
          ar  = __builtin_amdgcn_mfma_f32_16x16x32_bf16(Bf[jtl][0][0][kt], xf[kt], ar, 0, 0, 0);
          ar  = __builtin_amdgcn_mfma_f32_16x16x32_bf16(Bf[jtl][0][1][kt], hf[kt], ar, 0, 0, 0);
          az  = __builtin_amdgcn_mfma_f32_16x16x32_bf16(Bf[jtl][1][0][kt], xf[kt], az, 0, 0, 0);
          az  = __builtin_amdgcn_mfma_f32_16x16x32_bf16(Bf[jtl][1][1][kt], hf[kt], az, 0, 0, 0);
          ain = __builtin_amdgcn_mfma_f32_16x16x32_bf16(Bf[jtl][2][0][kt], xf[kt], ain, 0, 0, 0);
          ahn = __builtin_amdgcn_mfma_f32_16x16x32_bf16(Bf[jtl][2][1][kt], hf[kt], ahn, 0, 0, 0);
        }
        bf16x4 wv4;
#pragma unroll
        for (int q = 0; q < 4; ++q) {
          const float r_ = frcp(1.f + fex2(ar[q]));
          const float z_ = frcp(1.f + fex2(az[q]));
          const float s_ = ain[q] + r_ * (ahn[q] + bhnq[jtl][q]);
          const float n_ = fmaf(-2.f, frcp(1.f + fex2(s_)), 1.f);
          const float hv = n_ + z_ * (hold[mtl][jtl][q] - n_);
          hold[mtl][jtl][q] = hv;
          wv4[q] = (bf16)hv;
        }
        *(bf16x4*)(hw + mtl * 16 * LDP + jtl * 16) = wv4;   // h(t+1), b64
      }
    }
    __builtin_amdgcn_s_setprio(0);
  }
  __syncthreads();   // h(120) (written to plane 0 during t=119) visible

  // ---- epilogue: metric_fc (89->32, sigmoid), output_fc (32->1, sigmoid) ----
  for (int pp = tid; pp < BM * 32; pp += NTHR) {
    const int r = pp >> 5, c = pp & 31;
    const bf16* hr2 = &Hl[0][r][0];          // plain row-major final h
    const float* wrow = Wm + c * Hn;
    float acc = bm[c];
#pragma unroll 4
    for (int cb = 0; cb < 11; ++cb) {
      const bf16x8 hv = *(const bf16x8*)(hr2 + cb * 8);
      const f32x4 wa = ld4(wrow + cb * 8);
      const f32x4 wb = ld4(wrow + cb * 8 + 4);
      acc = fmaf((float)hv[0], wa[0], acc); acc = fmaf((float)hv[1], wa[1], acc);
      acc = fmaf((float)hv[2], wa[2], acc); acc = fmaf((float)hv[3], wa[3], acc);
      acc = fmaf((float)hv[4], wb[0], acc); acc = fmaf((float)hv[5], wb[1], acc);
      acc = fmaf((float)hv[6], wb[2], acc); acc = fmaf((float)hv[7], wb[3], acc);
    }
    acc = fmaf((float)hr2[88], wrow[88], acc);   // k=88
    const float mv = fsig(acc);
    Ml[r][c] = mv;
    Y[(size_t)Bt + (brow0 + r) * 32 + c] = mv;   // out_mmetric
  }
  __syncthreads();
  if (tid < BM) {
    float acc = bo[0];
#pragma unroll
    for (int c = 0; c < 32; ++c) acc = fmaf(Ml[tid][c], Wo[c], acc);
    Y[brow0 + tid] = fsig(acc);                  // out_mscore
  }
}

extern "C" void kernel_launch(void* const* d_in, const int* in_sizes, int n_in,
                              void* d_out, int out_size, void* d_ws, size_t ws_size,
                              hipStream_t stream) {
  const float* X   = (const float*)d_in[0];
  const float* Wih = (const float*)d_in[1];
  const float* Whh = (const float*)d_in[2];
  const float* bih = (const float*)d_in[3];
  const float* bhh = (const float*)d_in[4];
  const float* Wm  = (const float*)d_in[5];
  const float* bm  = (const float*)d_in[6];
  const float* Wo  = (const float*)d_in[7];
  const float* bo  = (const float*)d_in[8];

  const int B = in_sizes[0] / (Tn * Hn);   // 32768
  dim3 grid(B / BM), block(NTHR);
  gru_fused<<<grid, block, 0, stream>>>(X, Wih, Whh, bih, bhh, Wm, bm, Wo, bo,
                                        (float*)d_out, B);
}

// Round 14
// 626.411 us; speedup vs baseline: 6.4311x; 6.4311x over previous
//
#include <hip/hip_runtime.h>
#include <hip/hip_bf16.h>

#define Hn    89
#define Tn    120
#define BM    64
#define XPF   100                // X f32 LDS pitch
#define XPB   (XPF*4)            // 400 B
#define XPLANE (BM*XPB)          // 25600 B
#define HPB   208                // h bf16 pitch bytes
#define HPLANE (BM*HPB)          // 13312 B
#define ROWB  (Tn*Hn*4)          // 42720 B per batch row
#define TSTEP (Hn*4)             // 356
#define OMAX  ((unsigned)(BM*ROWB - 16))

#define SRZ (-1.44269504f)       // sigmoid pre-scale folded into r/z weights
#define SNN ( 2.88539008f)       // tanh pre-scale folded into n weights

using bf16   = __bf16;
using bf16x4 = __attribute__((ext_vector_type(4))) __bf16;
using bf16x8 = __attribute__((ext_vector_type(8))) __bf16;
typedef __attribute__((ext_vector_type(4))) float f32x4;

typedef const __attribute__((address_space(1))) unsigned int guint;
typedef __attribute__((address_space(3))) unsigned int luint;

__device__ __forceinline__ f32x4 ld4(const float* p) {
  f32x4 v; __builtin_memcpy(&v, p, 16); return v;
}
__device__ __forceinline__ bf16x8 pack8(f32x4 a, f32x4 b) {
  bf16x8 r;
  r[0]=(bf16)a[0]; r[1]=(bf16)a[1]; r[2]=(bf16)a[2]; r[3]=(bf16)a[3];
  r[4]=(bf16)b[0]; r[5]=(bf16)b[1]; r[6]=(bf16)b[2]; r[7]=(bf16)b[3];
  return r;
}
__device__ __forceinline__ float frcp(float x) { return __builtin_amdgcn_rcpf(x); }
__device__ __forceinline__ float fex2(float x) { return __builtin_amdgcn_exp2f(x); }
__device__ __forceinline__ float fsig(float x) { return frcp(1.f + fex2(-1.44269504f * x)); }

// 512-thread blocks, 2 blocks/CU -> two independent barrier domains.
// Waves 0-5: compute (one 16-j slice each, 18 weight frags = 72 VGPR);
// waves 6-7: producers, PURE global_load_lds DMA of X(t+1) + vmcnt(0).
// NO X patching (r13's cross-wave patch raced wave 6's DMA on cols 88/89):
// ALL matmul biases ride the h[89]==1.0 column on the hh side (Whh k=89 =
// SRZ*(bih+bhh) for r/z, SNN*bhh for n; Wih k=89 = 0), and b_in is a
// register fma (binq). X cols 89..99 hold next-step garbage x values ->
// multiplied by zero weight columns (finite, exact zero contribution).
// Tail backstop: the t=119/row-63 chunk clamp garbles real col 88; wave 7
// lane 63 rewrites that one f32 after ITS OWN vmcnt(0) (same-wave ordered).
// h carried only in LDS (bf16 roundtrip); one barrier per step.
__global__ __launch_bounds__(512, 4)
void gru_fused(const float* __restrict__ X,    // [B][T][89]
               const float* __restrict__ Wih,  // [267][89]
               const float* __restrict__ Whh,  // [267][89]
               const float* __restrict__ bih,  // [267]
               const float* __restrict__ bhh,  // [267]
               const float* __restrict__ Wm,   // [32][89]
               const float* __restrict__ bm,   // [32]
               const float* __restrict__ Wo,   // [32]
               const float* __restrict__ bo,   // [1]
               float* __restrict__ Y,          // [B] mscore | [B][32] mmetric
               int Bt)
{
  __shared__ __align__(16) char lds[2 * XPLANE + 2 * HPLANE];  // 77,824 B
  char* const XF0 = lds;
  char* const HL0 = lds + 2 * XPLANE;

  const int tid  = threadIdx.x;
  const int lane = tid & 63;
  const int wv   = tid >> 6;       // 0..7
  const int l15  = lane & 15;
  const int kg   = lane >> 4;      // 0..3
  const bool cmp = (wv < 6);
  const size_t brow0 = (size_t)blockIdx.x * BM;
  const char* xgw = (const char*)(X + brow0 * (size_t)(Tn * Hn));

  // ---- compute waves: weights -> 18 persistent A-frags (72 VGPR) ----
  bf16x8 Bf[3][2][3];  // [gate r/z/n][ih/hh][k-tile]
  float binq[4] = {0.f, 0.f, 0.f, 0.f};
  if (cmp) {
    const int jA = wv * 16 + l15;
    const bool jAok = (jA < Hn);
#pragma unroll
    for (int g = 0; g < 3; ++g)
#pragma unroll
      for (int s = 0; s < 2; ++s) {
        const float* W = s ? Whh : Wih;
        const float sc = (g < 2) ? SRZ : SNN;
#pragma unroll
        for (int kt = 0; kt < 3; ++kt) {
          bf16x8 f;
          const int k0 = kt * 32 + kg * 8;
#pragma unroll
          for (int e = 0; e < 8; ++e) {
            const int k = k0 + e;
            float v = 0.f;
            if (jAok) {
              if (k < Hn) v = sc * W[(size_t)(g * Hn + jA) * Hn + k];
              else if (k == Hn && s == 1)   // bias column, pairs with h[89]==1
                v = (g < 2) ? sc * (bih[g * Hn + jA] + bhh[g * Hn + jA])
                            : SNN * bhh[2 * Hn + jA];
            }
            f[e] = (bf16)v;
          }
          Bf[g][s][kt] = f;
        }
      }
#pragma unroll
    for (int q = 0; q < 4; ++q) {
      const int j = wv * 16 + kg * 4 + q;
      binq[q] = (j < Hn) ? SNN * bih[2 * Hn + j] : 0.f;
    }
  }

  // ---- producer staging: 25 chunks of 1KB (wave6: 0-12, wave7: 13-24) ----
  const unsigned cb   = (wv == 6) ? 0u : 3328u;  // chunk base (f32 idx)
  const int     nch   = (wv == 6) ? 13 : 12;
  const unsigned dstb = cb * 4u;                 // LDS byte base

  auto stage = [&](char* dst, unsigned toff) {   // producers only; pure DMA
    unsigned l4 = (unsigned)lane * 4u;
    asm volatile("" : "+v"(l4));                 // recompute offsets per call
#pragma unroll
    for (int m = 0; m < 13; ++m) {
      if (m < nch) {
        const unsigned idx4 = cb + (unsigned)(m * 256) + l4;
        const unsigned r = idx4 / 100u;
        const unsigned c = idx4 - r * 100u;
        unsigned o = r * (unsigned)ROWB + (c << 2) + toff;
        if (o > OMAX) o = OMAX;                  // tail clamp (see backstop)
        __builtin_amdgcn_global_load_lds(
            (guint*)(xgw + o), (luint*)(dst + dstb + (unsigned)(m * 1024)), 16, 0, 0);
      }
    }
    asm volatile("s_waitcnt vmcnt(0)" ::: "memory");   // this wave's DMA landed
    if (wv == 7 && lane == 63) {   // same-wave backstop: row 63 col 88
      const float x88 = *(const float*)(xgw + 63u * (unsigned)ROWB + 352u + toff);
      *(float*)(dst + 63 * XPB + 352) = x88;
    }
  };

  // ---- lane-constant compute bases (plane offsets added per step) ----
  const unsigned xro = (unsigned)(l15 * XPB + kg * 32);                // X frag
  const unsigned hro = (unsigned)(l15 * HPB + kg * 16);                // h frag
  const unsigned hwo = (unsigned)(l15 * HPB + (wv * 16 + kg * 4) * 2); // C/D b64

  // ---- prologue: X(0)->plane0 (producers), h(0)->plane0 (compute) ----
  if (cmp) {
    bf16x4 z4 = {(bf16)0.f, (bf16)0.f, (bf16)0.f, (bf16)0.f};
    if (wv == 5 && kg == 2) z4[1] = (bf16)1.0f;   // h[89] = 1.0 (bias column)
#pragma unroll
    for (int mt = 0; mt < 4; ++mt)
      *(bf16x4*)(HL0 + hwo + mt * 16 * HPB) = z4;
  } else {
    stage(XF0, 0);
  }

  unsigned tof = TSTEP;
  for (int t = 0; t < Tn; ++t) {
    const int b = t & 1;
    __syncthreads();                   // plane b: X(t), h(t) complete

    if (cmp) {
      __builtin_amdgcn_s_setprio(1);
      const char* xr = XF0 + b * XPLANE + xro;
      const char* hr = HL0 + b * HPLANE + hro;
      const char* hp = HL0 + b * HPLANE + hwo;            // own h(t) C/D slot
      char*       hw = HL0 + (b ^ 1) * HPLANE + hwo;
#pragma unroll
      for (int mt = 0; mt < 4; ++mt) {
        f32x4 ar = {0,0,0,0}, az = {0,0,0,0}, ain = {0,0,0,0}, ahn = {0,0,0,0};
#pragma unroll
        for (int kt = 0; kt < 3; ++kt) {
          const f32x4 xa = *(const f32x4*)(xr + mt * (16 * XPB) + kt * 128);
          const f32x4 xb = *(const f32x4*)(xr + mt * (16 * XPB) + kt * 128 + 16);
          const bf16x8 xf = pack8(xa, xb);
          const bf16x8 hf = *(const bf16x8*)(hr + mt * (16 * HPB) + kt * 64);
          ar  = __builtin_amdgcn_mfma_f32_16x16x32_bf16(Bf[0][0][kt], xf, ar, 0, 0, 0);
          ar  = __builtin_amdgcn_mfma_f32_16x16x32_bf16(Bf[0][1][kt], hf, ar, 0, 0, 0);
          az  = __builtin_amdgcn_mfma_f32_16x16x32_bf16(Bf[1][0][kt], xf, az, 0, 0, 0);
          az  = __builtin_amdgcn_mfma_f32_16x16x32_bf16(Bf[1][1][kt], hf, az, 0, 0, 0);
          ain = __builtin_amdgcn_mfma_f32_16x16x32_bf16(Bf[2][0][kt], xf, ain, 0, 0, 0);
          ahn = __builtin_amdgcn_mfma_f32_16x16x32_bf16(Bf[2][1][kt], hf, ahn, 0, 0, 0);
        }
        const bf16x4 hp4 = *(const bf16x4*)(hp + mt * (16 * HPB));
        bf16x4 wv4;
#pragma unroll
        for (int q = 0; q < 4; ++q) {
          const float r_ = frcp(1.f + fex2(ar[q]));
          const float z_ = frcp(1.f + fex2(az[q]));
          const float s_ = ain[q] + binq[q] + r_ * ahn[q];
          const float n_ = fmaf(-2.f, frcp(1.f + fex2(s_)), 1.f);
          const float hv = n_ + z_ * ((float)hp4[q] - n_);
          wv4[q] = (bf16)hv;
        }
        if (wv == 5) {   // j=80+4kg+q: force col89=1.0, cols>=90 -> 0
          if (kg == 2) { wv4[1] = (bf16)1.0f; wv4[2] = (bf16)0.f; wv4[3] = (bf16)0.f; }
          if (kg == 3) { wv4[0] = (bf16)0.f; wv4[1] = (bf16)0.f;
                         wv4[2] = (bf16)0.f; wv4[3] = (bf16)0.f; }
        }
        *(bf16x4*)(hw + mt * (16 * HPB)) = wv4;   // h(t+1), aligned b64
      }
      __builtin_amdgcn_s_setprio(0);
    } else {
      if (t + 1 < Tn) { stage(XF0 + (b ^ 1) * XPLANE, tof); tof += TSTEP; }
    }
  }
  __syncthreads();   // h(120) in HL plane 0

  // ---- epilogue: metric_fc (89->32, sigmoid), output_fc (32->1, sigmoid) ----
  char* const mlb = XF0;               // reuse X plane0: [64][32] f32
  for (int p = tid; p < BM * 32; p += 512) {
    const int r = p >> 5, c = p & 31;
    const char* hr2 = HL0 + r * HPB;
    const float* wrow = Wm + c * Hn;
    float acc = bm[c];
#pragma unroll 4
    for (int cbk = 0; cbk < 11; ++cbk) {
      const bf16x8 hv = *(const bf16x8*)(hr2 + cbk * 16);
      const f32x4 wa = ld4(wrow + cbk * 8);
      const f32x4 wb = ld4(wrow + cbk * 8 + 4);
      acc = fmaf((float)hv[0], wa[0], acc); acc = fmaf((float)hv[1], wa[1], acc);
      acc = fmaf((float)hv[2], wa[2], acc); acc = fmaf((float)hv[3], wa[3], acc);
      acc = fmaf((float)hv[4], wb[0], acc); acc = fmaf((float)hv[5], wb[1], acc);
      acc = fmaf((float)hv[6], wb[2], acc); acc = fmaf((float)hv[7], wb[3], acc);
    }
    acc = fmaf((float)*(const bf16*)(hr2 + 176), wrow[88], acc);   // k=88
    const float mv = fsig(acc);
    *(float*)(mlb + r * 128 + c * 4) = mv;
    Y[(size_t)Bt + (brow0 + r) * 32 + c] = mv;   // out_mmetric
  }
  __syncthreads();
  if (tid < BM) {
    float acc = bo[0];
#pragma unroll
    for (int c = 0; c < 32; ++c)
      acc = fmaf(*(const float*)(mlb + tid * 128 + c * 4), Wo[c], acc);
    Y[brow0 + tid] = fsig(acc);                  // out_mscore
  }
}

extern "C" void kernel_launch(void* const* d_in, const int* in_sizes, int n_in,
                              void* d_out, int out_size, void* d_ws, size_t ws_size,
                              hipStream_t stream) {
  const float* X   = (const float*)d_in[0];
  const float* Wih = (const float*)d_in[1];
  const float* Whh = (const float*)d_in[2];
  const float* bih = (const float*)d_in[3];
  const float* bhh = (const float*)d_in[4];
  const float* Wm  = (const float*)d_in[5];
  const float* bm  = (const float*)d_in[6];
  const float* Wo  = (const float*)d_in[7];
  const float* bo  = (const float*)d_in[8];

  const int B = in_sizes[0] / (Tn * Hn);   // 32768
  dim3 grid(B / BM), block(512);
  gru_fused<<<grid, block, 0, stream>>>(X, Wih, Whh, bih, bhh, Wm, bm, Wo, bo,
                                        (float*)d_out, B);
}